// Round 7
// baseline (480.707 us; speedup 1.0000x reference)
//
#include <hip/hip_runtime.h>
#include <math.h>
#include <stdint.h>

#define NV 8192        // N (nodes)
#define KD 256         // IN_DIM
#define DD 64          // OUT_DIM
#define ALPHA 0.2f
#define TI 64          // rows per block tile (4 waves x 16-row m-tiles)
#define SPLIT 16       // j-splits -> 2048 blocks
#define BLK 256

typedef _Float16 half8 __attribute__((ext_vector_type(8)));
typedef float floatx4 __attribute__((ext_vector_type(4)));
typedef int intx4 __attribute__((ext_vector_type(4)));

// ws layout (float offsets)
#define OFF_WHT  0                        // WhT f16 [DD][NV] = 262144 floats
#define OFF_F1   (DD * NV / 2)
#define OFF_F2   (OFF_F1 + NV)
#define OFF_M    (OFF_F2 + NV)
#define OFF_PACC (OFF_M + NV)             // then pacc[S][NV][DD], pl[S][NV]

// ---------------- kernel 1: WhT(f16) = (h@W)^T, f1 = Wh@a1, f2 = Wh@a2 ----------------
__global__ __launch_bounds__(256) void gat_pre(
    const float* __restrict__ h, const float* __restrict__ W,
    const float* __restrict__ a, ushort* __restrict__ whT,
    float* __restrict__ f1, float* __restrict__ f2) {
  __shared__ float hrow[16][KD];            // 16 KB
  __shared__ ushort tw[DD][20];             // transpose staging (+4 pad)
  const int tid = threadIdx.x;
  const int i0 = blockIdx.x * 16;
#pragma unroll
  for (int u = 0; u < 4; ++u) {
    const int idx = tid + u * 256;          // 1024 float4 slots = 16 rows x 64
    const int row = idx >> 6, col = (idx & 63) * 4;
    *(float4*)&hrow[row][col] = *(const float4*)&h[(long long)(i0 + row) * KD + col];
  }
  __syncthreads();
  const int d = tid & 63;                   // output col
  const int rg = tid >> 6;                  // wave -> 4 rows rg*4..rg*4+3
  float wh[4] = {0.f, 0.f, 0.f, 0.f};
#pragma unroll 4
  for (int c = 0; c < KD; ++c) {
    const float wc = W[c * DD + d];
#pragma unroll
    for (int r = 0; r < 4; ++r) wh[r] += hrow[rg * 4 + r][c] * wc;
  }
  const float a1 = a[d], a2 = a[DD + d];
#pragma unroll
  for (int r = 0; r < 4; ++r) {
    float p1 = wh[r] * a1, p2 = wh[r] * a2;
#pragma unroll
    for (int off = 32; off > 0; off >>= 1) {
      p1 += __shfl_down(p1, off);
      p2 += __shfl_down(p2, off);
    }
    if (d == 0) { f1[i0 + rg * 4 + r] = p1; f2[i0 + rg * 4 + r] = p2; }
    union { _Float16 hf; ushort u; } cv;
    cv.hf = (_Float16)wh[r];
    tw[d][rg * 4 + r] = cv.u;
  }
  __syncthreads();
  if (tid < 128) {                          // row d, 16 f16
    const int dd = tid >> 1, hf = tid & 1;
    *(uint4*)&whT[(long long)dd * NV + i0 + hf * 8] = *(uint4*)&tw[dd][hf * 8];
  }
}

// ---------------- kernel 1b: M[i] = lrelu(f1[i] + max_j f2[j]) ----------------
// One block. Removes the 32-load max-scan chain from all 2048 gat_main blocks.
__global__ __launch_bounds__(256) void gat_maxm(
    const float* __restrict__ f1, const float* __restrict__ f2,
    float* __restrict__ M) {
  __shared__ float red[4];
  const int tid = threadIdx.x;
  float m = -1e30f;
  for (int j = tid; j < NV; j += 256) m = fmaxf(m, f2[j]);
#pragma unroll
  for (int off = 32; off > 0; off >>= 1) m = fmaxf(m, __shfl_down(m, off));
  if ((tid & 63) == 0) red[tid >> 6] = m;
  __syncthreads();
  const float mm = fmaxf(fmaxf(red[0], red[1]), fmaxf(red[2], red[3]));
  for (int i = tid; i < NV; i += 256) {
    const float x = f1[i] + mm;             // upper bound of row max (lrelu monotone)
    M[i] = fmaxf(x, ALPHA * x);             // -> w <= 1, f16-safe
  }
}

// ---------------- kernel 2: fused masked-softmax attention @ Wh (MFMA f16) ----------------
// Barrier-free K-loop, operands in registers (R5/R6 verified mapping).
// R7: K-loop unrolled x2 with all 12 global loads grouped at iteration top (2x MLP);
// per-block f2max prologue removed (gat_maxm); A loads non-temporal (read-once
// stream, keep whT/f2 in L2). waves_per_eu(4,8) pins VGPR<=128 (anti-spill, R1/R2/R4).
__global__ __launch_bounds__(BLK) __attribute__((amdgpu_waves_per_eu(4, 8)))
void gat_main(
    const int* __restrict__ A, const ushort* __restrict__ whT,
    const float* __restrict__ f1, const float* __restrict__ Mv,
    const float* __restrict__ f2, float* __restrict__ pacc,
    float* __restrict__ pl, int S) {
  __shared__ float f2_lds[NV / SPLIT];   // 2 KB at S=16

  const int tid = threadIdx.x;
  const int wave = tid >> 6, lane = tid & 63;
  const int m_ = lane & 15, quad = lane >> 4;
  const int tile = blockIdx.x & 127;     // NV/TI = 128
  const int s = blockIdx.x >> 7;
  const int i0 = tile * TI;
  const int jrange = NV / S;             // 512
  const int j0 = s * jrange;

  // stage this block's f2 window (only LDS the K-loop touches)
  for (int u = tid * 4; u < jrange; u += BLK * 4)
    *(float4*)&f2_lds[u] = *(const float4*)&f2[j0 + u];

  const int row = i0 + wave * 16 + m_;
  const float f1r = f1[row];
  const float Mr = Mv[row];
  __syncthreads();

  floatx4 acc[4], accl;
#pragma unroll
  for (int nt = 0; nt < 4; ++nt) acc[nt] = (floatx4){0.f, 0.f, 0.f, 0.f};
  accl = (floatx4){0.f, 0.f, 0.f, 0.f};
  const half8 ones = {(_Float16)1.f, (_Float16)1.f, (_Float16)1.f, (_Float16)1.f,
                      (_Float16)1.f, (_Float16)1.f, (_Float16)1.f, (_Float16)1.f};

  const intx4* Arow = (const intx4*)(A + (long long)row * NV + j0 + quad * 8);  // index in intx4
  const ushort* Bb = whT + (long long)m_ * NV + j0 + quad * 8;

  for (int kb = 0; kb < jrange; kb += 64) {
    // ---- all 12 global loads issued together (2 k-windows) ----
    const intx4 a0 = __builtin_nontemporal_load(Arow + (kb >> 2));
    const intx4 a1 = __builtin_nontemporal_load(Arow + (kb >> 2) + 1);
    const intx4 a2 = __builtin_nontemporal_load(Arow + ((kb + 32) >> 2));
    const intx4 a3 = __builtin_nontemporal_load(Arow + ((kb + 32) >> 2) + 1);
    half8 b0[4], b1[4];
#pragma unroll
    for (int nt = 0; nt < 4; ++nt) {
      b0[nt] = *(const half8*)(Bb + (long long)(nt * 16) * NV + kb);
      b1[nt] = *(const half8*)(Bb + (long long)(nt * 16) * NV + kb + 32);
    }

    const int kk = kb + quad * 8;
    const float4 q0 = *(const float4*)&f2_lds[kk];
    const float4 q1 = *(const float4*)&f2_lds[kk + 4];
    const float4 q2 = *(const float4*)&f2_lds[kk + 32];
    const float4 q3 = *(const float4*)&f2_lds[kk + 36];

    union { _Float16 hf[8]; half8 v; } wfa, wfb;
#define WELT(dst, slot, aval, f2val)                                   \
    { float x = f1r + (f2val); x = fmaxf(x, ALPHA * x);                \
      float w = ((aval) > 0) ? __expf(x - Mr) : 0.f;                   \
      dst.hf[slot] = (_Float16)w; }
    WELT(wfa, 0, a0.x, q0.x) WELT(wfa, 1, a0.y, q0.y)
    WELT(wfa, 2, a0.z, q0.z) WELT(wfa, 3, a0.w, q0.w)
    WELT(wfa, 4, a1.x, q1.x) WELT(wfa, 5, a1.y, q1.y)
    WELT(wfa, 6, a1.z, q1.z) WELT(wfa, 7, a1.w, q1.w)
    WELT(wfb, 0, a2.x, q2.x) WELT(wfb, 1, a2.y, q2.y)
    WELT(wfb, 2, a2.z, q2.z) WELT(wfb, 3, a2.w, q2.w)
    WELT(wfb, 4, a3.x, q3.x) WELT(wfb, 5, a3.y, q3.y)
    WELT(wfb, 6, a3.z, q3.z) WELT(wfb, 7, a3.w, q3.w)
#undef WELT

#pragma unroll
    for (int nt = 0; nt < 4; ++nt)
      acc[nt] = __builtin_amdgcn_mfma_f32_16x16x32_f16(wfa.v, b0[nt], acc[nt], 0, 0, 0);
    accl = __builtin_amdgcn_mfma_f32_16x16x32_f16(wfa.v, ones, accl, 0, 0, 0);
#pragma unroll
    for (int nt = 0; nt < 4; ++nt)
      acc[nt] = __builtin_amdgcn_mfma_f32_16x16x32_f16(wfb.v, b1[nt], acc[nt], 0, 0, 0);
    accl = __builtin_amdgcn_mfma_f32_16x16x32_f16(wfb.v, ones, accl, 0, 0, 0);
  }

  // ---- pl from ones-MFMA: reg r = rowsum of i-row quad*4+r (same for all m_) ----
  if (m_ == 0) {
#pragma unroll
    for (int reg = 0; reg < 4; ++reg)
      pl[(long long)s * NV + i0 + wave * 16 + quad * 4 + reg] = accl[reg];
  }

  // ---- epilogue: C/D layout row=quad*4+reg, col=lane&15 (verified m89/m91) ----
#pragma unroll
  for (int reg = 0; reg < 4; ++reg) {
    const int i = i0 + wave * 16 + quad * 4 + reg;
    const long long base = ((long long)s * NV + i) * DD + m_;
#pragma unroll
    for (int nt = 0; nt < 4; ++nt) pacc[base + 16 * nt] = acc[nt][reg];
  }
}

// ---------------- kernel 3: combine j-splits, normalize, ELU ----------------
__global__ __launch_bounds__(256) void gat_fin(const float* __restrict__ pacc,
                                               const float* __restrict__ pl,
                                               float* __restrict__ out, int S) {
  const int idx = blockIdx.x * 256 + threadIdx.x;
  const int i = idx >> 6;
  float sum = 0.f, l = 0.f;
  for (int q = 0; q < S; ++q) sum += pacc[(long long)q * (NV * DD) + idx];
  for (int q = 0; q < S; ++q) l += pl[q * NV + i];
  const float v = sum / l;
  out[idx] = v > 0.f ? v : expm1f(v);  // ELU, alpha=1
}

extern "C" void kernel_launch(void* const* d_in, const int* in_sizes, int n_in,
                              void* d_out, int out_size, void* d_ws, size_t ws_size,
                              hipStream_t stream) {
  const float* h = (const float*)d_in[0];
  const int* A = (const int*)d_in[1];
  const float* W = (const float*)d_in[2];
  const float* a = (const float*)d_in[3];
  float* out = (float*)d_out;
  float* ws = (float*)d_ws;

  ushort* whT = (ushort*)(ws + OFF_WHT);
  float* f1 = ws + OFF_F1;
  float* f2 = ws + OFF_F2;
  float* Mv = ws + OFF_M;
  float* pacc = ws + OFF_PACC;

  const int S = SPLIT;  // pacc+pl at S=16: ~34 MB, well under ws_size (~1 GB)
  float* pl = pacc + (size_t)S * NV * DD;

  gat_pre<<<NV / 16, 256, 0, stream>>>(h, W, a, whT, f1, f2);
  gat_maxm<<<1, 256, 0, stream>>>(f1, f2, Mv);
  gat_main<<<(NV / TI) * S, BLK, 0, stream>>>(A, whT, f1, Mv, f2, pacc, pl, S);
  gat_fin<<<NV * DD / 256, 256, 0, stream>>>(pacc, pl, out, S);
}

// Round 8
// 432.371 us; speedup vs baseline: 1.1118x; 1.1118x over previous
//
#include <hip/hip_runtime.h>
#include <math.h>
#include <stdint.h>

#define NV 8192        // N (nodes)
#define KD 256         // IN_DIM
#define DD 64          // OUT_DIM
#define ALPHA 0.2f
#define TI 64          // rows per block tile
#define CJ 128         // j-chunk (16 chunks of 8 f16)
#define SPLIT 8        // j-splits -> 1024 blocks -> 4 blocks/CU (LDS-limited)
#define BLK 512

typedef _Float16 half8 __attribute__((ext_vector_type(8)));
typedef float floatx4 __attribute__((ext_vector_type(4)));

// ws layout (float offsets)
#define OFF_WHT  0                        // WhT f16 [DD][NV] = 262144 floats
#define OFF_F1   (DD * NV / 2)
#define OFF_F2   (OFF_F1 + NV)
#define OFF_M    (OFF_F2 + NV)
#define OFF_PACC (OFF_M + NV)             // then pacc[S][NV][DD], pl[S][NV]

// ---------------- kernel 1: WhT(f16) = (h@W)^T, f1 = Wh@a1, f2 = Wh@a2 ----------------
// 16 rows/block, 4 rows/thread (R4 version, measured clean).
__global__ __launch_bounds__(256) void gat_pre(
    const float* __restrict__ h, const float* __restrict__ W,
    const float* __restrict__ a, ushort* __restrict__ whT,
    float* __restrict__ f1, float* __restrict__ f2) {
  __shared__ float hrow[16][KD];            // 16 KB
  __shared__ ushort tw[DD][20];             // transpose staging (+4 pad)
  const int tid = threadIdx.x;
  const int i0 = blockIdx.x * 16;
#pragma unroll
  for (int u = 0; u < 4; ++u) {
    const int idx = tid + u * 256;          // 1024 float4 slots = 16 rows x 64
    const int row = idx >> 6, col = (idx & 63) * 4;
    *(float4*)&hrow[row][col] = *(const float4*)&h[(long long)(i0 + row) * KD + col];
  }
  __syncthreads();
  const int d = tid & 63;                   // output col
  const int rg = tid >> 6;                  // wave -> 4 rows rg*4..rg*4+3
  float wh[4] = {0.f, 0.f, 0.f, 0.f};
#pragma unroll 4
  for (int c = 0; c < KD; ++c) {
    const float wc = W[c * DD + d];
#pragma unroll
    for (int r = 0; r < 4; ++r) wh[r] += hrow[rg * 4 + r][c] * wc;
  }
  const float a1 = a[d], a2 = a[DD + d];
#pragma unroll
  for (int r = 0; r < 4; ++r) {
    float p1 = wh[r] * a1, p2 = wh[r] * a2;
#pragma unroll
    for (int off = 32; off > 0; off >>= 1) {
      p1 += __shfl_down(p1, off);
      p2 += __shfl_down(p2, off);
    }
    if (d == 0) { f1[i0 + rg * 4 + r] = p1; f2[i0 + rg * 4 + r] = p2; }
    union { _Float16 hf; ushort u; } cv;
    cv.hf = (_Float16)wh[r];
    tw[d][rg * 4 + r] = cv.u;
  }
  __syncthreads();
  if (tid < 128) {                          // row d, 16 f16
    const int dd = tid >> 1, hf = tid & 1;
    *(uint4*)&whT[(long long)dd * NV + i0 + hf * 8] = *(uint4*)&tw[dd][hf * 8];
  }
}

// ---------------- kernel 1b: M[i] = lrelu(f1[i] + max_j f2[j]) ----------------
__global__ __launch_bounds__(256) void gat_maxm(
    const float* __restrict__ f1, const float* __restrict__ f2,
    float* __restrict__ M) {
  __shared__ float red[4];
  const int tid = threadIdx.x;
  float m = -1e30f;
  for (int j = tid; j < NV; j += 256) m = fmaxf(m, f2[j]);
#pragma unroll
  for (int off = 32; off > 0; off >>= 1) m = fmaxf(m, __shfl_down(m, off));
  if ((tid & 63) == 0) red[tid >> 6] = m;
  __syncthreads();
  const float mm = fmaxf(fmaxf(red[0], red[1]), fmaxf(red[2], red[3]));
  for (int i = tid; i < NV; i += 256) {
    const float x = f1[i] + mm;             // upper bound of row max (lrelu monotone)
    M[i] = fmaxf(x, ALPHA * x);             // -> w <= 1, f16-safe
  }
}

// ---------------- kernel 2: fused masked-softmax attention @ Wh (MFMA f16) ----------------
// R3 structure (measured main ~70us): LDS-staged tiles, coalesced A loads
// (2 rows x 512 B contiguous per wave-instruction - NOT the 16-row/64B scatter
// of R5-R7, which halved effective memory throughput via L2-channel hotspot on
// the 32 KB power-of-2 row stride). Prologue f2-scan replaced by precomputed Mv.
__global__ __launch_bounds__(BLK) void gat_main(
    const int* __restrict__ A, const ushort* __restrict__ whT,
    const float* __restrict__ f1, const float* __restrict__ Mv,
    const float* __restrict__ f2, float* __restrict__ pacc,
    float* __restrict__ pl, int S) {
  __shared__ __align__(16) ushort w_lds[TI * CJ];  // 16 KB, A-operand (rows i)
  __shared__ __align__(16) ushort b_lds[TI * CJ];  // 16 KB, B-operand (rows d)
  __shared__ float f1_lds[TI], M_lds[TI];

  const int tid = threadIdx.x;
  const int wave = tid >> 6, lane = tid & 63;
  const int tile = blockIdx.x & 127;  // NV/TI = 128
  const int s = blockIdx.x >> 7;
  const int i0 = tile * TI;
  const int jrange = NV / S;
  const int j0 = s * jrange;

  if (tid < TI) {
    f1_lds[tid] = f1[i0 + tid];
    M_lds[tid] = Mv[i0 + tid];
  }

  // stage-1 mapping: thread covers cols c4..c4+3 of rows rb+16p
  const int c4 = (tid & 31) * 4;
  const int k8w = (tid & 31) >> 1;   // 16B-chunk col for writes
  const int sub = (tid & 1) * 8;     // byte offset within chunk
  const int rb = tid >> 5;           // 0..15
  // MFMA mapping: wave -> m-tile (wave>>1), two n-tiles
  const int mt = wave >> 1;
  const int nt0 = (wave & 1) * 2;
  const int m_ = lane & 15, quad = lane >> 4;

  floatx4 acc0 = {0.f, 0.f, 0.f, 0.f}, acc1 = {0.f, 0.f, 0.f, 0.f};
  float lp[4] = {0.f, 0.f, 0.f, 0.f};

  const int nch = jrange / CJ;
  for (int ch = 0; ch < nch; ++ch) {
    const int jb = j0 + ch * CJ;
    __syncthreads();  // previous chunk's LDS readers done (also covers f1/M init)

    // ---- stage B chunk: gather WhT with XOR swizzle into linear LDS ----
#pragma unroll
    for (int u = 0; u < 2; ++u) {
      const int idx = tid + u * BLK;  // 0..1023 chunk slots
      const int n = idx >> 4, c = idx & 15;
      const uint4 t = *(const uint4*)(whT + (long long)n * NV + jb + 8 * (c ^ (n & 15)));
      *(uint4*)&b_lds[idx * 8] = t;
    }

    // ---- stage 1: w = A ? exp(lrelu(f1+f2) - M) : 0, as f16 into w_lds ----
    const float4 f2v = *(const float4*)(f2 + jb + c4);
#pragma unroll
    for (int p = 0; p < 4; ++p) {
      const int r = rb + 16 * p;
      const int4 a4 = *(const int4*)(A + (long long)(i0 + r) * NV + jb + c4);
      const float f1r = f1_lds[r], Mr = M_lds[r];
      float w0, w1, w2, w3;
      { float x = f1r + f2v.x; x = fmaxf(x, ALPHA * x); w0 = (a4.x > 0) ? __expf(x - Mr) : 0.f; }
      { float x = f1r + f2v.y; x = fmaxf(x, ALPHA * x); w1 = (a4.y > 0) ? __expf(x - Mr) : 0.f; }
      { float x = f1r + f2v.z; x = fmaxf(x, ALPHA * x); w2 = (a4.z > 0) ? __expf(x - Mr) : 0.f; }
      { float x = f1r + f2v.w; x = fmaxf(x, ALPHA * x); w3 = (a4.w > 0) ? __expf(x - Mr) : 0.f; }
      union { _Float16 hf[4]; uint2 u2; } pk;
      pk.hf[0] = (_Float16)w0; pk.hf[1] = (_Float16)w1;
      pk.hf[2] = (_Float16)w2; pk.hf[3] = (_Float16)w3;
      // sum the f16-rounded values so softmax stays exactly normalized
      lp[p] += (float)pk.hf[0] + (float)pk.hf[1] + (float)pk.hf[2] + (float)pk.hf[3];
      *(uint2*)((char*)w_lds + (r * 16 + (k8w ^ (r & 15))) * 16 + sub) = pk.u2;
    }
    __syncthreads();

    // ---- stage 2: MFMA, 2 C-tiles per wave, 4 k-steps ----
#pragma unroll
    for (int ks = 0; ks < 4; ++ks) {
      const int cc = 4 * ks + quad;
      const half8 af = *(const half8*)((const char*)w_lds + (((16 * mt + m_) * 16) + (cc ^ m_)) * 16);
      const half8 b0 = *(const half8*)((const char*)b_lds + (((16 * nt0 + m_) * 16) + (cc ^ m_)) * 16);
      const half8 b1 = *(const half8*)((const char*)b_lds + (((16 * (nt0 + 1) + m_) * 16) + (cc ^ m_)) * 16);
      acc0 = __builtin_amdgcn_mfma_f32_16x16x32_f16(af, b0, acc0, 0, 0, 0);
      acc1 = __builtin_amdgcn_mfma_f32_16x16x32_f16(af, b1, acc1, 0, 0, 0);
    }
  }

  // ---- pl: reduce thread-local row-sum partials across each 32-lane group ----
#pragma unroll
  for (int p = 0; p < 4; ++p) {
    float v = lp[p];
    v += __shfl_down(v, 16, 32);
    v += __shfl_down(v, 8, 32);
    v += __shfl_down(v, 4, 32);
    v += __shfl_down(v, 2, 32);
    v += __shfl_down(v, 1, 32);
    if ((tid & 31) == 0) pl[(long long)s * NV + i0 + rb + 16 * p] = v;
  }

  // ---- epilogue: C/D layout row=quad*4+reg, col=lane&15 (verified m89/m91) ----
#pragma unroll
  for (int reg = 0; reg < 4; ++reg) {
    const int i = i0 + 16 * mt + quad * 4 + reg;
    const long long base = ((long long)s * NV + i) * DD + m_;
    pacc[base + 16 * nt0] = acc0[reg];
    pacc[base + 16 * (nt0 + 1)] = acc1[reg];
  }
}

// ---------------- kernel 3: combine j-splits, normalize, ELU ----------------
__global__ __launch_bounds__(256) void gat_fin(const float* __restrict__ pacc,
                                               const float* __restrict__ pl,
                                               float* __restrict__ out, int S) {
  const int idx = blockIdx.x * 256 + threadIdx.x;
  const int i = idx >> 6;
  float sum = 0.f, l = 0.f;
  for (int q = 0; q < S; ++q) sum += pacc[(long long)q * (NV * DD) + idx];
  for (int q = 0; q < S; ++q) l += pl[q * NV + i];
  const float v = sum / l;
  out[idx] = v > 0.f ? v : expm1f(v);  // ELU, alpha=1
}

extern "C" void kernel_launch(void* const* d_in, const int* in_sizes, int n_in,
                              void* d_out, int out_size, void* d_ws, size_t ws_size,
                              hipStream_t stream) {
  const float* h = (const float*)d_in[0];
  const int* A = (const int*)d_in[1];
  const float* W = (const float*)d_in[2];
  const float* a = (const float*)d_in[3];
  float* out = (float*)d_out;
  float* ws = (float*)d_ws;

  ushort* whT = (ushort*)(ws + OFF_WHT);
  float* f1 = ws + OFF_F1;
  float* f2 = ws + OFF_F2;
  float* Mv = ws + OFF_M;
  float* pacc = ws + OFF_PACC;

  const int S = SPLIT;  // pacc+pl at S=8: ~17 MB, well under ws_size (~1 GB)
  float* pl = pacc + (size_t)S * NV * DD;

  gat_pre<<<NV / 16, 256, 0, stream>>>(h, W, a, whT, f1, f2);
  gat_maxm<<<1, 256, 0, stream>>>(f1, f2, Mv);
  gat_main<<<(NV / TI) * S, BLK, 0, stream>>>(A, whT, f1, Mv, f2, pacc, pl, S);
  gat_fin<<<NV * DD / 256, 256, 0, stream>>>(pacc, pl, out, S);
}